// Round 1
// baseline (408.686 us; speedup 1.0000x reference)
//
#include <hip/hip_runtime.h>
#include <math.h>

#define D_MODEL   512
#define MAX_PL    32
#define TGT       4
#define G_TILES   16
#define R_TILES   32
#define NTHREADS  256

// Block = 256 threads, handles G_TILES=16 consecutive (n,r) tiles.
// Thread t owns output dims d0=2t, 2t+1 for all tiles/k — its w_emb rows for
// all 3 tables live in registers (112 VGPRs), so embedding-table traffic is
// one table read per block instead of per output element.
__global__ __launch_bounds__(NTHREADS, 2)
void ape_main(const float* __restrict__ x,
              const float* __restrict__ w1, const float* __restrict__ b1,
              const float* __restrict__ w2, const float* __restrict__ b2,
              const float* __restrict__ we0, const float* __restrict__ we1,
              const float* __restrict__ we2,
              float* __restrict__ out)
{
    __shared__ float xs[G_TILES * MAX_PL];   // 16 tiles x 32 samples
    __shared__ float hbuf[G_TILES * 64];     // hidden activations
    __shared__ int   preds[G_TILES];

    const int t = threadIdx.x;
    const long long tile0 = (long long)blockIdx.x * G_TILES;

    // ---- stage x (contiguous: tile nr starts at nr*32) ----
    {
        const float* xb = x + tile0 * MAX_PL;
        xs[t]       = xb[t];
        xs[t + 256] = xb[t + 256];
    }
    __syncthreads();

    // ---- hidden layer: h = relu(xr @ w1^T + b1), 16 tiles x 64 units ----
    {
        const int hidx = t & 63;
        const float* w1r = w1 + hidx * MAX_PL;
        float wreg[MAX_PL];
        #pragma unroll
        for (int p = 0; p < MAX_PL; ++p) wreg[p] = w1r[p];
        const float bb = b1[hidx];
        const int gbase = t >> 6;
        #pragma unroll
        for (int gg = 0; gg < 4; ++gg) {
            const int g = gbase + gg * 4;
            float acc = 0.f;
            #pragma unroll
            for (int p = 0; p < MAX_PL; ++p)
                acc = fmaf(wreg[p], xs[g * MAX_PL + p], acc);
            acc += bb;
            hbuf[g * 64 + hidx] = fmaxf(acc, 0.f);
        }
    }
    __syncthreads();

    // ---- logits + argmax (first-max tie-break, matches np.argmax) ----
    if (t < G_TILES) {
        const float* hg = hbuf + t * 64;
        float l[3];
        #pragma unroll
        for (int e = 0; e < 3; ++e) {
            const float* w2r = w2 + e * 64;
            float acc = 0.f;
            for (int h = 0; h < 64; ++h) acc = fmaf(w2r[h], hg[h], acc);
            l[e] = acc + b2[e];
        }
        int bi = 0; float best = l[0];
        if (l[1] > best) { best = l[1]; bi = 1; }
        if (l[2] > best) { bi = 2; }
        preds[t] = bi;
    }

    // ---- preload this thread's w_emb rows (dims d0, d0+1) for all 3 tables ----
    const int d0 = t << 1;
    float r0[2][8]  __attribute__((aligned(16)));
    float r1[2][16] __attribute__((aligned(16)));
    float r2[2][32] __attribute__((aligned(16)));
    {
        const float4* s0 = (const float4*)(we0 + (size_t)d0 * 8);
        float4* q0 = (float4*)&r0[0][0];
        #pragma unroll
        for (int i = 0; i < 4; ++i) q0[i] = s0[i];
        const float4* s1 = (const float4*)(we1 + (size_t)d0 * 16);
        float4* q1 = (float4*)&r1[0][0];
        #pragma unroll
        for (int i = 0; i < 8; ++i) q1[i] = s1[i];
        const float4* s2 = (const float4*)(we2 + (size_t)d0 * 32);
        float4* q2 = (float4*)&r2[0][0];
        #pragma unroll
        for (int i = 0; i < 16; ++i) q2[i] = s2[i];
    }

    // PE frequency for this dim pair: exp(d_even * -(ln(10000)/512))
    const float freq = expf((float)d0 * -0.017988946f);

    __syncthreads();

    // ---- per-tile embedding + PE + store ----
    for (int g = 0; g < G_TILES; ++g) {
        const int pred = preds[g];
        const long long tile = tile0 + g;
        const int r = (int)(tile & (R_TILES - 1));
        float* obase = out + tile * (TGT * D_MODEL);
        const float* xv = xs + g * MAX_PL;

        float v[TGT][2];
        if (pred == 0) {            // pl=8: 4 distinct patches
            #pragma unroll
            for (int k = 0; k < 4; ++k) {
                float a0 = 0.f, a1 = 0.f;
                #pragma unroll
                for (int j = 0; j < 8; ++j) {
                    const float xx = xv[k * 8 + j];
                    a0 = fmaf(r0[0][j], xx, a0);
                    a1 = fmaf(r0[1][j], xx, a1);
                }
                v[k][0] = a0; v[k][1] = a1;
            }
        } else if (pred == 1) {     // pl=16: repeat idx [0,0,0,1]
            float bt[2][2];
            #pragma unroll
            for (int kp = 0; kp < 2; ++kp) {
                float a0 = 0.f, a1 = 0.f;
                #pragma unroll
                for (int j = 0; j < 16; ++j) {
                    const float xx = xv[kp * 16 + j];
                    a0 = fmaf(r1[0][j], xx, a0);
                    a1 = fmaf(r1[1][j], xx, a1);
                }
                bt[kp][0] = a0; bt[kp][1] = a1;
            }
            v[0][0] = bt[0][0]; v[0][1] = bt[0][1];
            v[1][0] = bt[0][0]; v[1][1] = bt[0][1];
            v[2][0] = bt[0][0]; v[2][1] = bt[0][1];
            v[3][0] = bt[1][0]; v[3][1] = bt[1][1];
        } else {                    // pl=32: one patch, repeated 4x
            float a0 = 0.f, a1 = 0.f;
            #pragma unroll
            for (int j = 0; j < 32; ++j) {
                const float xx = xv[j];
                a0 = fmaf(r2[0][j], xx, a0);
                a1 = fmaf(r2[1][j], xx, a1);
            }
            #pragma unroll
            for (int k = 0; k < 4; ++k) { v[k][0] = a0; v[k][1] = a1; }
        }

        #pragma unroll
        for (int k = 0; k < 4; ++k) {
            float s, c;
            sincosf((float)(r * TGT + k) * freq, &s, &c);
            float2 o;
            o.x = v[k][0] + s;   // even dim: sin
            o.y = v[k][1] + c;   // odd dim: cos
            *(float2*)(obase + k * D_MODEL + d0) = o;
        }
    }
}

// Second tuple output: the scalar C (=21) appended after x_patch.
__global__ void ape_tail(float* p, int n) {
    int i = blockIdx.x * blockDim.x + threadIdx.x;
    if (i < n) p[i] = 21.0f;
}

extern "C" void kernel_launch(void* const* d_in, const int* in_sizes, int n_in,
                              void* d_out, int out_size, void* d_ws, size_t ws_size,
                              hipStream_t stream)
{
    const float* x   = (const float*)d_in[0];
    const float* w1  = (const float*)d_in[1];
    const float* b1  = (const float*)d_in[2];
    const float* w2  = (const float*)d_in[3];
    const float* b2  = (const float*)d_in[4];
    const float* we0 = (const float*)d_in[5];
    const float* we1 = (const float*)d_in[6];
    const float* we2 = (const float*)d_in[7];
    float* out = (float*)d_out;

    const long long NR = (long long)in_sizes[0] / MAX_PL;   // B*C*R = 43008
    const int nblocks = (int)(NR / G_TILES);
    ape_main<<<nblocks, NTHREADS, 0, stream>>>(x, w1, b1, w2, b2, we0, we1, we2, out);

    const long long main_elems = NR * (long long)(TGT * D_MODEL);
    if ((long long)out_size > main_elems) {
        const int tail = (int)((long long)out_size - main_elems);
        ape_tail<<<(tail + 63) / 64, 64, 0, stream>>>(out + main_elems, tail);
    }
}

// Round 2
// 399.627 us; speedup vs baseline: 1.0227x; 1.0227x over previous
//
#include <hip/hip_runtime.h>
#include <math.h>

#define D_MODEL   512
#define MAX_PL    32
#define TGT       4
#define G_TILES   16
#define R_TILES   32
#define NTHREADS  256

// Block = 256 threads, handles G_TILES=16 consecutive (n,r) tiles.
// Thread t owns output dims d0=2t, 2t+1; its w_emb rows for all 3 tables live
// in registers (112 VGPRs). PE sin/cos advanced by rotation recurrence
// (positions are an arithmetic sequence per block) -> 3 sincosf total.
__global__ __launch_bounds__(NTHREADS, 2)
void ape_main(const float* __restrict__ x,
              const float* __restrict__ w1, const float* __restrict__ b1,
              const float* __restrict__ w2, const float* __restrict__ b2,
              const float* __restrict__ we0, const float* __restrict__ we1,
              const float* __restrict__ we2,
              float* __restrict__ out)
{
    __shared__ float xs[G_TILES * MAX_PL];   // 16 tiles x 32 samples
    __shared__ float hbuf[G_TILES * 64];     // hidden activations
    __shared__ float lbuf[G_TILES * 3];      // logits
    __shared__ int   preds[G_TILES];

    const int t = threadIdx.x;
    const long long tile0 = (long long)blockIdx.x * G_TILES;

    // ---- stage x (contiguous: tile nr starts at nr*32) ----
    {
        const float* xb = x + tile0 * MAX_PL;
        xs[t]       = xb[t];
        xs[t + 256] = xb[t + 256];
    }
    __syncthreads();

    // ---- hidden layer: h = relu(xr @ w1^T + b1), 16 tiles x 64 units ----
    {
        const int hidx = t & 63;
        float wreg[MAX_PL] __attribute__((aligned(16)));
        {
            const float4* w1q = (const float4*)(w1 + hidx * MAX_PL);
            float4* wq = (float4*)wreg;
            #pragma unroll
            for (int i = 0; i < 8; ++i) wq[i] = w1q[i];
        }
        const float bb = b1[hidx];
        const int gbase = t >> 6;
        #pragma unroll
        for (int gg = 0; gg < 4; ++gg) {
            const int g = gbase + gg * 4;
            float acc = 0.f;
            #pragma unroll
            for (int p = 0; p < MAX_PL; ++p)
                acc = fmaf(wreg[p], xs[g * MAX_PL + p], acc);
            acc += bb;
            hbuf[g * 64 + hidx] = fmaxf(acc, 0.f);
        }
    }
    __syncthreads();

    // ---- logits (48 threads: tile g, expert e) + argmax (16 threads) ----
    // All within wave 0 -> in-wave LDS ordering, no extra barrier needed.
    if (t < 48) {
        const int g = t / 3, e = t - g * 3;
        const float* hg = hbuf + g * 64;
        const float* w2r = w2 + e * 64;
        float acc = 0.f;
        #pragma unroll 8
        for (int h = 0; h < 64; ++h) acc = fmaf(w2r[h], hg[h], acc);
        lbuf[g * 3 + e] = acc + b2[e];
    }
    if (t < G_TILES) {
        const float l0 = lbuf[t * 3], l1 = lbuf[t * 3 + 1], l2 = lbuf[t * 3 + 2];
        int bi = 0; float best = l0;
        if (l1 > best) { best = l1; bi = 1; }
        if (l2 > best) { bi = 2; }
        preds[t] = bi;
    }

    // ---- preload this thread's w_emb rows (dims d0, d0+1) for all 3 tables ----
    const int d0 = t << 1;
    float r0[2][8]  __attribute__((aligned(16)));
    float r1[2][16] __attribute__((aligned(16)));
    float r2[2][32] __attribute__((aligned(16)));
    {
        const float4* s0 = (const float4*)(we0 + (size_t)d0 * 8);
        float4* q0 = (float4*)&r0[0][0];
        #pragma unroll
        for (int i = 0; i < 4; ++i) q0[i] = s0[i];
        const float4* s1 = (const float4*)(we1 + (size_t)d0 * 16);
        float4* q1 = (float4*)&r1[0][0];
        #pragma unroll
        for (int i = 0; i < 8; ++i) q1[i] = s1[i];
        const float4* s2 = (const float4*)(we2 + (size_t)d0 * 32);
        float4* q2 = (float4*)&r2[0][0];
        #pragma unroll
        for (int i = 0; i < 16; ++i) q2[i] = s2[i];
    }

    // ---- PE via rotation recurrence: pos = pos0 + 4g + k ----
    const float freq = expf((float)d0 * -0.017988946f);  // -ln(10000)/512
    const int   r0i  = (int)(tile0 & (R_TILES - 1));     // 0 or 16
    float s1r, c1r, s4r, c4r, sg, cg;
    sincosf(freq, &s1r, &c1r);
    sincosf(4.0f * freq, &s4r, &c4r);
    sincosf((float)(r0i * TGT) * freq, &sg, &cg);

    __syncthreads();

    // ---- per-tile embedding + PE + store ----
    for (int g = 0; g < G_TILES; ++g) {
        const int pred = preds[g];
        const long long tile = tile0 + g;
        float* obase = out + tile * (TGT * D_MODEL) + d0;

        // tile x -> registers via ds_read_b128 (shared by all pred paths)
        float xq[MAX_PL] __attribute__((aligned(16)));
        {
            const float4* xv4 = (const float4*)(xs + g * MAX_PL);
            float4* xr4 = (float4*)xq;
            #pragma unroll
            for (int i = 0; i < 8; ++i) xr4[i] = xv4[i];
        }

        float v[TGT][2];
        if (pred == 0) {            // pl=8: 4 distinct patches
            #pragma unroll
            for (int k = 0; k < 4; ++k) {
                float a0 = 0.f, a1 = 0.f;
                #pragma unroll
                for (int j = 0; j < 8; ++j) {
                    const float xx = xq[k * 8 + j];
                    a0 = fmaf(r0[0][j], xx, a0);
                    a1 = fmaf(r0[1][j], xx, a1);
                }
                v[k][0] = a0; v[k][1] = a1;
            }
        } else if (pred == 1) {     // pl=16: repeat idx [0,0,0,1]
            float bt[2][2];
            #pragma unroll
            for (int kp = 0; kp < 2; ++kp) {
                float a0 = 0.f, a1 = 0.f;
                #pragma unroll
                for (int j = 0; j < 16; ++j) {
                    const float xx = xq[kp * 16 + j];
                    a0 = fmaf(r1[0][j], xx, a0);
                    a1 = fmaf(r1[1][j], xx, a1);
                }
                bt[kp][0] = a0; bt[kp][1] = a1;
            }
            v[0][0] = bt[0][0]; v[0][1] = bt[0][1];
            v[1][0] = bt[0][0]; v[1][1] = bt[0][1];
            v[2][0] = bt[0][0]; v[2][1] = bt[0][1];
            v[3][0] = bt[1][0]; v[3][1] = bt[1][1];
        } else {                    // pl=32: one patch, repeated 4x
            float a0 = 0.f, a1 = 0.f;
            #pragma unroll
            for (int j = 0; j < 32; ++j) {
                const float xx = xq[j];
                a0 = fmaf(r2[0][j], xx, a0);
                a1 = fmaf(r2[1][j], xx, a1);
            }
            #pragma unroll
            for (int k = 0; k < 4; ++k) { v[k][0] = a0; v[k][1] = a1; }
        }

        // k-loop: rotate (sk,ck) by angle freq each step; streaming stores
        float sk = sg, ck = cg;
        #pragma unroll
        for (int k = 0; k < 4; ++k) {
            float2 o;
            o.x = v[k][0] + sk;   // even dim: sin
            o.y = v[k][1] + ck;   // odd dim: cos
            __builtin_nontemporal_store(*(const unsigned long long*)&o,
                                        (unsigned long long*)(obase + k * D_MODEL));
            const float ns = fmaf(sk, c1r,  ck * s1r);
            const float nc = fmaf(ck, c1r, -sk * s1r);
            sk = ns; ck = nc;
        }
        // advance base by 4 positions for next tile
        const float ns = fmaf(sg, c4r,  cg * s4r);
        const float nc = fmaf(cg, c4r, -sg * s4r);
        sg = ns; cg = nc;
    }
}

// Second tuple output: the scalar C (=21) appended after x_patch.
__global__ void ape_tail(float* p, int n) {
    int i = blockIdx.x * blockDim.x + threadIdx.x;
    if (i < n) p[i] = 21.0f;
}

extern "C" void kernel_launch(void* const* d_in, const int* in_sizes, int n_in,
                              void* d_out, int out_size, void* d_ws, size_t ws_size,
                              hipStream_t stream)
{
    const float* x   = (const float*)d_in[0];
    const float* w1  = (const float*)d_in[1];
    const float* b1  = (const float*)d_in[2];
    const float* w2  = (const float*)d_in[3];
    const float* b2  = (const float*)d_in[4];
    const float* we0 = (const float*)d_in[5];
    const float* we1 = (const float*)d_in[6];
    const float* we2 = (const float*)d_in[7];
    float* out = (float*)d_out;

    const long long NR = (long long)in_sizes[0] / MAX_PL;   // B*C*R = 43008
    const int nblocks = (int)(NR / G_TILES);
    ape_main<<<nblocks, NTHREADS, 0, stream>>>(x, w1, b1, w2, b2, we0, we1, we2, out);

    const long long main_elems = NR * (long long)(TGT * D_MODEL);
    if ((long long)out_size > main_elems) {
        const int tail = (int)((long long)out_size - main_elems);
        ape_tail<<<(tail + 63) / 64, 64, 0, stream>>>(out + main_elems, tail);
    }
}